// Round 1
// baseline (75.839 us; speedup 1.0000x reference)
//
#include <hip/hip_runtime.h>

#define BB 8
#define NC 12
#define NC1 11
#define HH 512
#define WW 512
#define NCH 32      // h-chunks per column
#define HC 16       // h per chunk (NCH*HC == HH)
#define NBC (BB*NC1) // 88 (b,c) slices

static constexpr size_t CH_STRIDE = (size_t)HH * WW;   // 262144

// output offsets (flat floats, in return order)
static constexpr size_t OFF_LSM   = 0;
static constexpr size_t OFF_CLP   = 23068672;  // + 8*11*512*512
static constexpr size_t OFF_CLEAN = 23113728;  // + 8*11*512
static constexpr size_t OFF_STD   = 48279552;  // + 8*12*512*512
static constexpr size_t OFF_TOPO  = 48324608;  // + 8*11*512
static constexpr size_t OFF_CONT  = 48365568;  // + 8*10*512
static constexpr size_t OFF_CURV  = 48410536;  // + 8*11*511

// workspace layout (floats)
static constexpr size_t WS_E    = 0;                              // [88][32][512] -> later chunk cum-bases
static constexpr size_t WS_P    = (size_t)NBC * NCH * WW;         // 1441792
static constexpr size_t WS_Q    = 2 * WS_P;
static constexpr size_t WS_INVS = 3 * WS_P;                       // [88][512]
static constexpr size_t WS_LOGS = WS_INVS + (size_t)NBC * WW;
static constexpr size_t WS_LP   = WS_LOGS + (size_t)NBC * WW;
// total = WS_LP + 88*512 = 4460544 floats = 17.8 MB

// ---------------------------------------------------------------- K1: chunk partial sums
__global__ __launch_bounds__(512) void k1_partials(const float* __restrict__ in,
                                                   float* __restrict__ ws) {
    const int w = threadIdx.x;
    const int chunk = blockIdx.x;      // 0..NCH-1
    const int bc = blockIdx.y;         // 0..87
    const int b = bc / NC1, c = bc % NC1;

    const float* p = in + ((size_t)(b * NC + c) * HH + (size_t)chunk * HC) * WW + w;
    float E = 0.f, P = 0.f, Q = 0.f;
#pragma unroll
    for (int i = 0; i < HC; ++i) {
        float x = p[(size_t)i * WW];
        float e = expf(x);
        float h = (float)(chunk * HC + i);
        E += e;
        P += h * e;
        Q += h * h * e;
    }
    size_t o = ((size_t)bc * NCH + chunk) * WW + w;
    ws[WS_E + o] = E;
    ws[WS_P + o] = P;
    ws[WS_Q + o] = Q;
}

// ---------------------------------------------------------------- K2: per-column reduce, bases, std
__global__ __launch_bounds__(512) void k2_reduce(float* __restrict__ ws,
                                                 float* __restrict__ out) {
    const int w = threadIdx.x;
    const int bc = blockIdx.x;  // 0..87

    const size_t base0 = (size_t)bc * NCH * WW + w;
    float Ee[NCH];
    double S = 0.0, P = 0.0, Q = 0.0;
#pragma unroll
    for (int k = 0; k < NCH; ++k) {
        float e = ws[WS_E + base0 + (size_t)k * WW];
        Ee[k] = e;
        S += (double)e;
        P += (double)ws[WS_P + base0 + (size_t)k * WW];
        Q += (double)ws[WS_Q + base0 + (size_t)k * WW];
    }
    const double inv = 1.0 / S;
    double pre = 0.0;
#pragma unroll
    for (int k = 0; k < NCH; ++k) {  // normalized cumsum base before each chunk (in place over E)
        ws[WS_E + base0 + (size_t)k * WW] = (float)(pre * inv);
        pre += (double)Ee[k];
    }
    const double lp = P * inv;
    double var = Q * inv - lp * lp;
    if (var < 0.0) var = 0.0;

    const size_t o = (size_t)bc * WW + w;
    ws[WS_INVS + o] = (float)inv;
    ws[WS_LOGS + o] = (float)log(S);
    ws[WS_LP + o]   = (float)lp;
    out[OFF_STD + o] = (float)sqrt(var);
}

// ---------------------------------------------------------------- K3: lp-derived small outputs
__global__ __launch_bounds__(512) void k3_small(const float* __restrict__ lp,
                                                float* __restrict__ out) {
    const int w = threadIdx.x;   // 0..511
    const int b = blockIdx.x;    // 0..7
    const float CM[NC1] = {1.2261f, 1.1558f, 1.1161f, 1.1195f, 2.7202f, 2.3714f,
                           1.7055f, 3.2717f, 2.6716f, 5.0418f, 0.4293f};
    float lpv[NC1];
#pragma unroll
    for (int c = 0; c < NC1; ++c)
        lpv[c] = lp[(size_t)(b * NC1 + c) * WW + w];

    // cummax over classes
    float m = lpv[0];
#pragma unroll
    for (int c = 0; c < NC1; ++c) {
        m = fmaxf(m, lpv[c]);
        out[OFF_CLP + (size_t)(b * NC1 + c) * WW + w] = m;
    }
    // topology: relu(lp[c] - lp[c+1])
#pragma unroll
    for (int c = 0; c < NC1 - 1; ++c)
        out[OFF_TOPO + (size_t)(b * (NC1 - 1) + c) * WW + w] = fmaxf(lpv[c] - lpv[c + 1], 0.f);
    // continuity: |lp[w] - lp[w+1]| at j = w (j in 0..510)
    if (w < WW - 1) {
#pragma unroll
        for (int c = 0; c < NC1; ++c) {
            float nxt = lp[(size_t)(b * NC1 + c) * WW + w + 1];
            out[OFF_CONT + (size_t)(b * NC1 + c) * (WW - 1) + w] = fabsf(lpv[c] - nxt);
        }
    }
    // curvature (edge-padded by 5)
    const int wm = (w - 5 < 0) ? 0 : w - 5;
    const int wp = (w + 5 > WW - 1) ? WW - 1 : w + 5;
#pragma unroll
    for (int c = 0; c < NC1; ++c) {
        float a  = lp[(size_t)(b * NC1 + c) * WW + wm];
        float bb = lp[(size_t)(b * NC1 + c) * WW + wp];
        float fo = bb - a;
        float so = a - 2.f * lpv[c] + bb;
        float bs = 1.f + fo * fo;
        float cv = so / (bs * sqrtf(bs));
        out[OFF_CURV + (size_t)(b * NC1 + c) * WW + w] = fabsf(cv) - CM[c];
    }
}

// ---------------------------------------------------------------- K4: lsm + clean_masks
__global__ __launch_bounds__(256) void k4_main(const float* __restrict__ in,
                                               const float* __restrict__ ws,
                                               float* __restrict__ out) {
    const int tid = threadIdx.x;
    const int whalf = blockIdx.x;   // 0..1
    const int chunk = blockIdx.y;   // 0..NCH-1
    const int b = blockIdx.z;       // 0..7
    const int w = whalf * 256 + tid;

    float cum[NC1], inv[NC1], lgs[NC1];
#pragma unroll
    for (int c = 0; c < NC1; ++c) {
        size_t bc = (size_t)(b * NC1 + c);
        cum[c] = ws[WS_E + (bc * NCH + chunk) * WW + w];
        inv[c] = ws[WS_INVS + bc * WW + w];
        lgs[c] = ws[WS_LOGS + bc * WW + w];
    }

    for (int i = 0; i < HC; ++i) {
        const int h = chunk * HC + i;
        float x[NC1];
#pragma unroll
        for (int c = 0; c < NC1; ++c)
            x[c] = in[(size_t)(b * NC + c) * CH_STRIDE + (size_t)h * WW + w];
#pragma unroll
        for (int c = 0; c < NC1; ++c) {
            cum[c] += expf(x[c]) * inv[c];
            out[OFF_LSM + (size_t)(b * NC1 + c) * CH_STRIDE + (size_t)h * WW + w] = x[c] - lgs[c];
        }
        // cross-class relu chain -> clean_masks (12 channels)
        const size_t ob = OFF_CLEAN + (size_t)(b * NC) * CH_STRIDE + (size_t)h * WW + w;
        float tc = cum[0];
        out[ob] = 1.f - tc;
#pragma unroll
        for (int k = 1; k < NC1; ++k) {
            float t2 = fmaxf(cum[k] + tc - 1.f, 0.f);
            out[ob + (size_t)k * CH_STRIDE] = tc - t2;
            tc = t2;
        }
        out[ob + (size_t)NC1 * CH_STRIDE] = tc;
    }
}

extern "C" void kernel_launch(void* const* d_in, const int* in_sizes, int n_in,
                              void* d_out, int out_size, void* d_ws, size_t ws_size,
                              hipStream_t stream) {
    const float* in = (const float*)d_in[0];
    float* out = (float*)d_out;
    float* ws = (float*)d_ws;

    hipLaunchKernelGGL(k1_partials, dim3(NCH, NBC), dim3(512), 0, stream, in, ws);
    hipLaunchKernelGGL(k2_reduce, dim3(NBC), dim3(512), 0, stream, ws, out);
    hipLaunchKernelGGL(k3_small, dim3(BB), dim3(512), 0, stream, ws + WS_LP, out);
    hipLaunchKernelGGL(k4_main, dim3(2, NCH, BB), dim3(256), 0, stream, in, ws, out);
}